// Round 8
// baseline (521.791 us; speedup 1.0000x reference)
//
#include <hip/hip_runtime.h>
#include <math.h>

#define T_SEQ 2048
#define CDIM 1024
#define NH 16
#define NKV 4
#define HS 64
#define FIRE_N 1024   // interpolation intervals; table has FIRE_N+1 entries

typedef __attribute__((ext_vector_type(8))) short bf16x8;
typedef __attribute__((ext_vector_type(4))) float f32x4;
typedef __attribute__((ext_vector_type(4))) unsigned short ushort4v;

__device__ __forceinline__ unsigned short f2bf(float f) {
    unsigned int u = __float_as_uint(f);
    u += 0x7fff + ((u >> 16) & 1);   // RNE
    return (unsigned short)(u >> 16);
}

// ---------------- float atomics via CAS ----------------
__device__ __forceinline__ void atomicMinF(float* addr, float val) {
    unsigned int* ua = (unsigned int*)addr;
    unsigned int old = __float_as_uint(*addr);
    while (val < __uint_as_float(old)) {
        unsigned int assumed = old;
        old = atomicCAS(ua, assumed, __float_as_uint(val));
        if (old == assumed) break;
    }
}
__device__ __forceinline__ void atomicMaxF(float* addr, float val) {
    unsigned int* ua = (unsigned int*)addr;
    unsigned int old = __float_as_uint(*addr);
    while (val > __uint_as_float(old)) {
        unsigned int assumed = old;
        old = atomicCAS(ua, assumed, __float_as_uint(val));
        if (old == assumed) break;
    }
}

// ---------------- init: rope tables, FIRE 1-D tables, minmax slots ----------------
__global__ __launch_bounds__(256) void init_kernel(float* cosT, float* sinT, float* rdT,
                                                   float* pnT, float* mm,
                                                   const float* fire_c, const float* fire_L) {
    int i = blockIdx.x * 256 + threadIdx.x;
    float c = fire_c[0];
    float L = fabsf(fire_L[0]);
    if (i < T_SEQ * 32) {
        int t = i >> 5, j = i & 31;
        float inv = powf(10000.0f, -(float)j / 32.0f);
        float f = (float)t * inv;
        cosT[i] = cosf(f);
        sinT[i] = sinf(f);
    }
    if (i < T_SEQ) {
        rdT[i] = logf(fabsf(c * (float)i) + 1.0f);
        pnT[i] = logf(fabsf(c * fmaxf((float)i, L)) + 1.0f) + 1e-6f;
    }
    if (i < 16) mm[i] = (i & 1) ? -__builtin_inff() : __builtin_inff();
}

// ---------------- FIRE bias(nd) piecewise-linear table, per head ----------------
__global__ __launch_bounds__(256) void fire_table_kernel(float* __restrict__ fireT,
    const float* __restrict__ w1, const float* __restrict__ b1,
    const float* __restrict__ w2, const float* __restrict__ b2,
    const float* __restrict__ fc, const float* __restrict__ fL) {
    int h = blockIdx.x;
    float cc = fabsf(fc[0]), LL = fabsf(fL[0]);
    float pn_min = logf(cc * LL + 1.0f) + 1e-6f;
    float ndmax = logf(cc * 2047.0f + 1.0f) / pn_min;
    float step = (ndmax > 1e-30f) ? (ndmax / (float)FIRE_N) : 0.0f;
    float b2h = b2[h];
    for (int i = threadIdx.x; i < FIRE_N + 1; i += 256) {
        float nd = step * (float)i;
        float acc = b2h;
        #pragma unroll
        for (int j = 0; j < 32; ++j)
            acc += fmaxf(fmaf(nd, w1[j], b1[j]), 0.0f) * w2[j * NH + h];
        fireT[h * (FIRE_N + 1) + i] = acc;
    }
}

// ---------------- fp32 -> bf16 elementwise convert ----------------
__global__ __launch_bounds__(256) void cvt_bf16_kernel(const float* __restrict__ in,
                                                       unsigned short* __restrict__ out, int n4) {
    for (int i = blockIdx.x * 256 + threadIdx.x; i < n4; i += gridDim.x * 256) {
        float4 v = ((const float4*)in)[i];
        ushort4v o;
        o[0] = f2bf(v.x); o[1] = f2bf(v.y); o[2] = f2bf(v.z); o[3] = f2bf(v.w);
        ((ushort4v*)out)[i] = o;
    }
}

// ---------------- transpose + convert: in (R x C fp32) -> out (C x R bf16) ----------------
// grid: (C/64, R/64), 256 threads.
__global__ __launch_bounds__(256) void transpose_bf16_kernel(const float* __restrict__ in,
                                                             unsigned short* __restrict__ out,
                                                             int R, int C) {
    __shared__ float t[64][65];
    int c0 = blockIdx.x * 64, r0 = blockIdx.y * 64;
    int tid = threadIdx.x;
    int lr = tid >> 6, lc = tid & 63;
    #pragma unroll 4
    for (int i = 0; i < 16; ++i)
        t[lr + 4 * i][lc] = in[(size_t)(r0 + lr + 4 * i) * C + c0 + lc];
    __syncthreads();
    #pragma unroll 4
    for (int i = 0; i < 16; ++i)
        out[(size_t)(c0 + lr + 4 * i) * R + r0 + lc] = f2bf(t[lc][lr + 4 * i]);
}

// ---------------- bf16 MFMA GEMM: C(MxN fp32) = A(MxK bf16) @ Bt(NxK bf16)^T ----------------
// 128x128 tile, 4 waves each owning a 64x64 quadrant, BK=32 (one MFMA depth).
// LDS rows padded to 40 elems (80B) -> 2-way bank aliasing only (free).
__global__ __launch_bounds__(256) void gemm_bf16(const unsigned short* __restrict__ A,
                                                 const unsigned short* __restrict__ Bt,
                                                 float* __restrict__ C,
                                                 int M, int N, int K) {
    __shared__ unsigned short As[128 * 40];
    __shared__ unsigned short Bs[128 * 40];
    const int tid = threadIdx.x;
    const int row0 = blockIdx.y * 128, col0 = blockIdx.x * 128;
    const int wv = tid >> 6, lane = tid & 63;
    const int l15 = lane & 15, l4 = lane >> 4;
    const int wr = (wv >> 1) * 64, wc = (wv & 1) * 64;
    f32x4 acc[4][4];
    #pragma unroll
    for (int n = 0; n < 4; ++n)
        #pragma unroll
        for (int m = 0; m < 4; ++m) acc[n][m] = (f32x4){0.f, 0.f, 0.f, 0.f};

    for (int k0 = 0; k0 < K; k0 += 32) {
        #pragma unroll
        for (int t2 = 0; t2 < 2; ++t2) {
            int c = tid + t2 * 256;
            int r = c >> 2, qq = c & 3;
            uint4 av = *(const uint4*)(A + (size_t)(row0 + r) * K + k0 + qq * 8);
            *(uint4*)(As + r * 40 + qq * 8) = av;
            uint4 bv = *(const uint4*)(Bt + (size_t)(col0 + r) * K + k0 + qq * 8);
            *(uint4*)(Bs + r * 40 + qq * 8) = bv;
        }
        __syncthreads();
        bf16x8 af[4], bfr[4];
        #pragma unroll
        for (int n = 0; n < 4; ++n) af[n] = *(const bf16x8*)(As + (wr + n * 16 + l15) * 40 + l4 * 8);
        #pragma unroll
        for (int m = 0; m < 4; ++m) bfr[m] = *(const bf16x8*)(Bs + (wc + m * 16 + l15) * 40 + l4 * 8);
        #pragma unroll
        for (int n = 0; n < 4; ++n)
            #pragma unroll
            for (int m = 0; m < 4; ++m)
                acc[n][m] = __builtin_amdgcn_mfma_f32_16x16x32_bf16(af[n], bfr[m], acc[n][m], 0, 0, 0);
        __syncthreads();
    }
    // C/D layout (m89/m91-verified): col = lane&15 (B index), row = (lane>>4)*4 + reg (A index)
    #pragma unroll
    for (int n = 0; n < 4; ++n) {
        #pragma unroll
        for (int m = 0; m < 4; ++m) {
            #pragma unroll
            for (int j = 0; j < 4; ++j) {
                C[(size_t)(row0 + wr + n * 16 + l4 * 4 + j) * N + col0 + wc + m * 16 + l15] = acc[n][m][j];
            }
        }
    }
}

// ---------------- RoPE in place + global min/max ----------------
__global__ __launch_bounds__(256) void rope_minmax_kernel(float* __restrict__ x,
                                                          const float* __restrict__ cosT,
                                                          const float* __restrict__ sinT,
                                                          int nh, float* mm) {
    int n = T_SEQ * nh * 32;
    float lmn = __builtin_inff(), lmx = -__builtin_inff();
    for (int i = blockIdx.x * 256 + threadIdx.x; i < n; i += gridDim.x * 256) {
        int d = i & 31;
        int th = i >> 5;
        int h = th % nh;
        int t = th / nh;
        float c = cosT[(t << 5) + d], s = sinT[(t << 5) + d];
        float* p = x + ((size_t)t * nh + h) * 64;
        float x1 = p[d], x2 = p[d + 32];
        float o1 = fmaf(x1, c, -x2 * s);
        float o2 = fmaf(x2, c, x1 * s);
        p[d] = o1;
        p[d + 32] = o2;
        lmn = fminf(lmn, fminf(o1, o2));
        lmx = fmaxf(lmx, fmaxf(o1, o2));
    }
    __shared__ float smn[256], smx[256];
    int tid = threadIdx.x;
    smn[tid] = lmn; smx[tid] = lmx;
    __syncthreads();
    for (int s2 = 128; s2; s2 >>= 1) {
        if (tid < s2) {
            smn[tid] = fminf(smn[tid], smn[tid + s2]);
            smx[tid] = fmaxf(smx[tid], smx[tid + s2]);
        }
        __syncthreads();
    }
    if (tid == 0) { atomicMinF(mm, smn[0]); atomicMaxF(mm + 1, smx[0]); }
}

// ---------------- plain global min/max ----------------
__global__ __launch_bounds__(256) void minmax_kernel(const float* __restrict__ x, int n, float* mm) {
    float lmn = __builtin_inff(), lmx = -__builtin_inff();
    for (int i = blockIdx.x * 256 + threadIdx.x; i < n; i += gridDim.x * 256) {
        float v = x[i];
        lmn = fminf(lmn, v);
        lmx = fmaxf(lmx, v);
    }
    __shared__ float smn[256], smx[256];
    int tid = threadIdx.x;
    smn[tid] = lmn; smx[tid] = lmx;
    __syncthreads();
    for (int s2 = 128; s2; s2 >>= 1) {
        if (tid < s2) {
            smn[tid] = fminf(smn[tid], smn[tid + s2]);
            smx[tid] = fmaxf(smx[tid], smx[tid + s2]);
        }
        __syncthreads();
    }
    if (tid == 0) { atomicMinF(mm, smn[0]); atomicMaxF(mm + 1, smx[0]); }
}

// ---------------- fake-quant fp32 -> bf16 out (for q,k,v,y) ----------------
__global__ __launch_bounds__(256) void quant_bf16_kernel(const float* __restrict__ x, int n,
                                                         const float* __restrict__ mm,
                                                         unsigned short* __restrict__ out) {
    float mn = mm[0], mx = mm[1];
    float scale = (mx - mn) / 255.0f + 1e-12f;
    float zp = rintf(-mn / scale);
    for (int i = blockIdx.x * 256 + threadIdx.x; i < n; i += gridDim.x * 256) {
        float v = x[i];
        float qv = rintf(v / scale) + zp;
        qv = fminf(fmaxf(qv, 0.0f), 255.0f);
        out[i] = f2bf((qv - zp) * scale);
    }
}

// ---------------- MFMA flash attention (v2: dbuf prefetch, 1 barrier/tile, LPT) ----------------
// Block: (q-tile of 64 rows, head), qt = 31 - blockIdx.x (heavy tiles dispatch first).
// K and V^T double-buffered in LDS; next tile's global loads issued BEFORE computing
// the current tile (T14 issue-early/write-late) so HBM/L2 latency hides under compute.
// One __syncthreads per tile. Ps is wave-private (no cross-wave sync needed; same-wave
// LDS ops execute in order). Math is bit-identical to v1.
__global__ __launch_bounds__(256) void attn_mfma(
    const unsigned short* __restrict__ qb, const unsigned short* __restrict__ kb,
    const unsigned short* __restrict__ vb, float* __restrict__ y,
    const float* __restrict__ rdT, const float* __restrict__ pnT,
    const float* __restrict__ fireT,
    const float* __restrict__ fc, const float* __restrict__ fL) {
    __shared__ __align__(16) char Ks[2][8192];
    __shared__ __align__(16) char Vt[2][8192];
    __shared__ __align__(16) char Ps[8192];
    __shared__ float biasT[FIRE_N + 1];
    __shared__ float rdS[T_SEQ];

    const int h = blockIdx.y, g = h >> 2;
    const int qt = (int)(gridDim.x - 1) - (int)blockIdx.x;   // LPT ordering
    const int q0 = qt << 6;
    const int tid = threadIdx.x;
    const int w = tid >> 6, lane = tid & 63;
    const int l15 = lane & 15, l4 = lane >> 4;
    const int nt = qt + 1;

    for (int i = tid; i < FIRE_N + 1; i += 256) biasT[i] = fireT[h * (FIRE_N + 1) + i];
    for (int i = tid; i < T_SEQ; i += 256) rdS[i] = rdT[i];

    float cc = fabsf(fc[0]), LL = fabsf(fL[0]);
    float pn_min = logf(cc * LL + 1.0f) + 1e-6f;
    float ndmax = logf(cc * 2047.0f + 1.0f) / pn_min;
    float inv_step = (ndmax > 1e-30f) ? ((float)FIRE_N / ndmax) : 0.0f;

    int qrow[4]; float invpn[4], mreg[4], lreg[4];
    #pragma unroll
    for (int r = 0; r < 4; ++r) {
        qrow[r] = q0 + (w << 4) + (l4 << 2) + r;
        invpn[r] = 1.0f / pnT[qrow[r]];
        mreg[r] = -3.0e38f; lreg[r] = 0.0f;
    }

    // Q A-fragments kept in registers for the whole kernel
    bf16x8 qa[2];
    {
        int qr = q0 + (w << 4) + l15;
        const unsigned short* qp = qb + ((size_t)qr * NH + h) * HS + (l4 << 3);
        qa[0] = *(const bf16x8*)(qp);
        qa[1] = *(const bf16x8*)(qp + 32);
    }

    const int krow = tid >> 2, kqtr = tid & 3;        // K staging role
    const int ksw = (krow & 7) << 4;
    const int vk = tid & 63, vd0 = (tid >> 6) << 4;   // V staging role

    // staging register buffers (prefetch lives here across compute)
    uint4 kRa, kRb, vRa, vRb;
    auto loadK = [&](int tt) {
        const unsigned short* kp = kb + (((size_t)((tt << 6) + krow) * NKV + g) << 6) + (kqtr << 4);
        kRa = *(const uint4*)(kp);
        kRb = *(const uint4*)(kp + 8);
    };
    auto storeK = [&](int b) {
        *(uint4*)(Ks[b] + krow * 128 + ((kqtr << 5) ^ ksw)) = kRa;
        *(uint4*)(Ks[b] + krow * 128 + (((kqtr << 5) + 16) ^ ksw)) = kRb;
    };
    auto loadV = [&](int tt) {
        const unsigned short* vp = vb + (((size_t)((tt << 6) + vk) * NKV + g) << 6) + vd0;
        vRa = *(const uint4*)(vp);
        vRb = *(const uint4*)(vp + 8);
    };
    auto storeV = [&](int b) {
        unsigned int wv2[8] = {vRa.x, vRa.y, vRa.z, vRa.w, vRb.x, vRb.y, vRb.z, vRb.w};
        int k2 = vk << 1;
        #pragma unroll
        for (int i = 0; i < 8; ++i) {
            int d = vd0 + (i << 1);
            *(unsigned short*)(Vt[b] + d * 128 + (k2 ^ ((d & 7) << 4))) = (unsigned short)(wv2[i] & 0xffff);
            int d1 = d + 1;
            *(unsigned short*)(Vt[b] + d1 * 128 + (k2 ^ ((d1 & 7) << 4))) = (unsigned short)(wv2[i] >> 16);
        }
    };

    // ---------------- pass A: online m,l ----------------
    loadK(0); storeK(0);
    __syncthreads();                       // covers table fills + buf0
    for (int tt = 0; tt < nt; ++tt) {
        const int cur = tt & 1;
        if (tt + 1 < nt) loadK(tt + 1);    // issue next tile early
        f32x4 s[4];
        #pragma unroll
        for (int n = 0; n < 4; ++n) s[n] = (f32x4){0.f, 0.f, 0.f, 0.f};
        #pragma unroll
        for (int ks = 0; ks < 2; ++ks) {
            int cb = (l4 << 4) + (ks << 6);
            #pragma unroll
            for (int n = 0; n < 4; ++n) {
                int rowk = (n << 4) + l15;
                bf16x8 kf = *(const bf16x8*)(Ks[cur] + rowk * 128 + (cb ^ ((rowk & 7) << 4)));
                s[n] = __builtin_amdgcn_mfma_f32_16x16x32_bf16(qa[ks], kf, s[n], 0, 0, 0);
            }
        }
        #pragma unroll
        for (int n = 0; n < 4; ++n) {
            int kidx = (tt << 6) + (n << 4) + l15;
            #pragma unroll
            for (int r = 0; r < 4; ++r) {
                float v;
                if (kidx <= qrow[r]) {
                    float nd = rdS[qrow[r] - kidx] * invpn[r];
                    float u = nd * inv_step;
                    int iu = (int)u; iu = min(iu, FIRE_N - 1);
                    float fr = u - (float)iu;
                    float b0 = biasT[iu];
                    v = fmaf(s[n][r], 0.125f, fmaf(fr, biasT[iu + 1] - b0, b0));
                } else v = -3.0e38f;
                s[n][r] = v;
            }
        }
        #pragma unroll
        for (int r = 0; r < 4; ++r) {
            float tmax = fmaxf(fmaxf(s[0][r], s[1][r]), fmaxf(s[2][r], s[3][r]));
            tmax = fmaxf(tmax, __shfl_xor(tmax, 1));
            tmax = fmaxf(tmax, __shfl_xor(tmax, 2));
            tmax = fmaxf(tmax, __shfl_xor(tmax, 4));
            tmax = fmaxf(tmax, __shfl_xor(tmax, 8));
            float mnew = fmaxf(mreg[r], tmax);
            float es = __expf(s[0][r] - mnew) + __expf(s[1][r] - mnew)
                     + __expf(s[2][r] - mnew) + __expf(s[3][r] - mnew);
            es += __shfl_xor(es, 1); es += __shfl_xor(es, 2);
            es += __shfl_xor(es, 4); es += __shfl_xor(es, 8);
            lreg[r] = lreg[r] * __expf(mreg[r] - mnew) + es;
            mreg[r] = mnew;
        }
        if (tt + 1 < nt) storeK(cur ^ 1);  // write-late (waits only its own vmcnt)
        __syncthreads();                   // release cur for overwrite in tt+2
    }

    float invl[4];
    #pragma unroll
    for (int r = 0; r < 4; ++r) invl[r] = 1.0f / lreg[r];

    // ---------------- pass B: recompute scores, quantized PV ----------------
    f32x4 yacc[4];
    #pragma unroll
    for (int n = 0; n < 4; ++n) yacc[n] = (f32x4){0.f, 0.f, 0.f, 0.f};

    loadK(0); loadV(0); storeK(0); storeV(0);
    __syncthreads();
    for (int tt = 0; tt < nt; ++tt) {
        const int cur = tt & 1;
        if (tt + 1 < nt) { loadK(tt + 1); loadV(tt + 1); }
        f32x4 s[4];
        #pragma unroll
        for (int n = 0; n < 4; ++n) s[n] = (f32x4){0.f, 0.f, 0.f, 0.f};
        #pragma unroll
        for (int ks = 0; ks < 2; ++ks) {
            int cb = (l4 << 4) + (ks << 6);
            #pragma unroll
            for (int n = 0; n < 4; ++n) {
                int rowk = (n << 4) + l15;
                bf16x8 kf = *(const bf16x8*)(Ks[cur] + rowk * 128 + (cb ^ ((rowk & 7) << 4)));
                s[n] = __builtin_amdgcn_mfma_f32_16x16x32_bf16(qa[ks], kf, s[n], 0, 0, 0);
            }
        }
        #pragma unroll
        for (int n = 0; n < 4; ++n) {
            int kidx = (tt << 6) + (n << 4) + l15;
            #pragma unroll
            for (int r = 0; r < 4; ++r) {
                float v;
                if (kidx <= qrow[r]) {
                    float nd = rdS[qrow[r] - kidx] * invpn[r];
                    float u = nd * inv_step;
                    int iu = (int)u; iu = min(iu, FIRE_N - 1);
                    float fr = u - (float)iu;
                    float b0 = biasT[iu];
                    v = fmaf(s[n][r], 0.125f, fmaf(fr, biasT[iu + 1] - b0, b0));
                } else v = -3.0e38f;
                s[n][r] = v;
            }
        }
        // p = exp(s-m)/l, quantize to 1/255 grid, stage as bf16 A-operand.
        // Ps rows are wave-private -> no barrier between write and read.
        #pragma unroll
        for (int n = 0; n < 4; ++n) {
            #pragma unroll
            for (int r = 0; r < 4; ++r) {
                float p = __expf(s[n][r] - mreg[r]) * invl[r];
                float ph = fminf(rintf(p * 255.0f), 255.0f) * (1.0f / 255.0f);
                int rowp = (w << 4) + (l4 << 2) + r;
                *(unsigned short*)(Ps + rowp * 128 + ((((n << 4) + l15) << 1) ^ ((rowp & 7) << 4))) = f2bf(ph);
            }
        }
        #pragma unroll
        for (int ks = 0; ks < 2; ++ks) {
            int rowp = (w << 4) + l15;
            int cb = (l4 << 4) + (ks << 6);
            bf16x8 pa = *(const bf16x8*)(Ps + rowp * 128 + (cb ^ ((rowp & 7) << 4)));
            #pragma unroll
            for (int n2 = 0; n2 < 4; ++n2) {
                int d = (n2 << 4) + l15;
                bf16x8 vf = *(const bf16x8*)(Vt[cur] + d * 128 + (cb ^ ((d & 7) << 4)));
                yacc[n2] = __builtin_amdgcn_mfma_f32_16x16x32_bf16(pa, vf, yacc[n2], 0, 0, 0);
            }
        }
        if (tt + 1 < nt) { storeK(cur ^ 1); storeV(cur ^ 1); }
        __syncthreads();
    }

    #pragma unroll
    for (int n2 = 0; n2 < 4; ++n2)
        #pragma unroll
        for (int r = 0; r < 4; ++r)
            y[((size_t)qrow[r] * NH + h) * HS + (n2 << 4) + l15] = yacc[n2][r];
}

extern "C" void kernel_launch(void* const* d_in, const int* in_sizes, int n_in,
                              void* d_out, int out_size, void* d_ws, size_t ws_size,
                              hipStream_t stream) {
    const float* x     = (const float*)d_in[0];
    const float* Wq    = (const float*)d_in[1];
    const float* Wk    = (const float*)d_in[2];
    const float* Wv    = (const float*)d_in[3];
    const float* Wproj = (const float*)d_in[4];
    const float* fw1   = (const float*)d_in[5];
    const float* fb1   = (const float*)d_in[6];
    const float* fw2   = (const float*)d_in[7];
    const float* fb2   = (const float*)d_in[8];
    const float* fc    = (const float*)d_in[9];
    const float* fL    = (const float*)d_in[10];
    float* out = (float*)d_out;

    float* ws   = (float*)d_ws;
    float* qf   = ws;                  // (T,16,64) fp32 q; REUSED as y after quant
    float* kkf  = qf + 2097152;        // (T,4,64) fp32
    float* vvf  = kkf + 524288;
    float* cosT = vvf + 524288;
    float* sinT = cosT + 65536;
    float* rdT  = sinT + 65536;
    float* pnT  = rdT + 2048;
    float* mm   = pnT + 2048;          // [qmn,qmx,kmn,kmx,vmn,vmx,ymn,ymx]
    float* fireT = mm + 16;            // 16*(FIRE_N+1)
    unsigned short* qb  = (unsigned short*)(fireT + 16 * (FIRE_N + 1));
    unsigned short* kb  = qb + 2097152;
    unsigned short* vb  = kb + 524288;
    unsigned short* xb  = vb + 524288;       // (T,1024) bf16; REUSED as yb
    unsigned short* Wqt = xb + 2097152;      // (1024,1024) bf16 transposed
    unsigned short* Wkt = Wqt + 1048576;     // (256,1024)
    unsigned short* Wvt = Wkt + 262144;      // (256,1024)
    unsigned short* Wpt = Wvt + 262144;      // (1024,1024)
    float* y  = qf;                    // alias: q fp32 dead after quant_bf16
    unsigned short* yb = xb;           // alias: xb dead after projections

    init_kernel<<<256, 256, 0, stream>>>(cosT, sinT, rdT, pnT, mm, fc, fL);
    fire_table_kernel<<<16, 256, 0, stream>>>(fireT, fw1, fb1, fw2, fb2, fc, fL);

    // convert x and transpose+convert weights to bf16
    cvt_bf16_kernel<<<1024, 256, 0, stream>>>(x, xb, 524288);
    transpose_bf16_kernel<<<dim3(16, 16), 256, 0, stream>>>(Wq, Wqt, 1024, 1024);
    transpose_bf16_kernel<<<dim3(4, 16), 256, 0, stream>>>(Wk, Wkt, 1024, 256);
    transpose_bf16_kernel<<<dim3(4, 16), 256, 0, stream>>>(Wv, Wvt, 1024, 256);
    transpose_bf16_kernel<<<dim3(16, 16), 256, 0, stream>>>(Wproj, Wpt, 1024, 1024);

    // projections (MFMA)
    gemm_bf16<<<dim3(8, 16), 256, 0, stream>>>(xb, Wqt, qf, T_SEQ, CDIM, CDIM);
    gemm_bf16<<<dim3(2, 16), 256, 0, stream>>>(xb, Wkt, kkf, T_SEQ, 256, CDIM);
    gemm_bf16<<<dim3(2, 16), 256, 0, stream>>>(xb, Wvt, vvf, T_SEQ, 256, CDIM);

    rope_minmax_kernel<<<1024, 256, 0, stream>>>(qf, cosT, sinT, NH, mm + 0);
    rope_minmax_kernel<<<512, 256, 0, stream>>>(kkf, cosT, sinT, NKV, mm + 2);
    minmax_kernel<<<512, 256, 0, stream>>>(vvf, 524288, mm + 4);

    quant_bf16_kernel<<<1024, 256, 0, stream>>>(qf, 2097152, mm + 0, qb);
    quant_bf16_kernel<<<512, 256, 0, stream>>>(kkf, 524288, mm + 2, kb);
    quant_bf16_kernel<<<512, 256, 0, stream>>>(vvf, 524288, mm + 4, vb);

    dim3 ga(T_SEQ / 64, NH);
    attn_mfma<<<ga, 256, 0, stream>>>(qb, kb, vb, y, rdT, pnT, fireT, fc, fL);

    minmax_kernel<<<1024, 256, 0, stream>>>(y, 2097152, mm + 6);
    quant_bf16_kernel<<<1024, 256, 0, stream>>>(y, 2097152, mm + 6, yb);

    // output projection (MFMA)
    gemm_bf16<<<dim3(8, 16), 256, 0, stream>>>(yb, Wpt, out, T_SEQ, CDIM, CDIM);
}

// Round 10
// 462.914 us; speedup vs baseline: 1.1272x; 1.1272x over previous
//
#include <hip/hip_runtime.h>
#include <math.h>

#define T_SEQ 2048
#define CDIM 1024
#define NH 16
#define NKV 4
#define HS 64
#define FIRE_N 1024   // interpolation intervals; table has FIRE_N+1 entries

typedef __attribute__((ext_vector_type(8))) short bf16x8;
typedef __attribute__((ext_vector_type(4))) float f32x4;
typedef __attribute__((ext_vector_type(4))) unsigned short ushort4v;

__device__ __forceinline__ unsigned short f2bf(float f) {
    unsigned int u = __float_as_uint(f);
    u += 0x7fff + ((u >> 16) & 1);   // RNE
    return (unsigned short)(u >> 16);
}

// ---------------- float atomics via CAS ----------------
__device__ __forceinline__ void atomicMinF(float* addr, float val) {
    unsigned int* ua = (unsigned int*)addr;
    unsigned int old = __float_as_uint(*addr);
    while (val < __uint_as_float(old)) {
        unsigned int assumed = old;
        old = atomicCAS(ua, assumed, __float_as_uint(val));
        if (old == assumed) break;
    }
}
__device__ __forceinline__ void atomicMaxF(float* addr, float val) {
    unsigned int* ua = (unsigned int*)addr;
    unsigned int old = __float_as_uint(*addr);
    while (val > __uint_as_float(old)) {
        unsigned int assumed = old;
        old = atomicCAS(ua, assumed, __float_as_uint(val));
        if (old == assumed) break;
    }
}

// ---------------- init: rope tables, FIRE 1-D tables, minmax slots ----------------
__global__ __launch_bounds__(256) void init_kernel(float* cosT, float* sinT, float* rdT,
                                                   float* pnT, float* mm,
                                                   const float* fire_c, const float* fire_L) {
    int i = blockIdx.x * 256 + threadIdx.x;
    float c = fire_c[0];
    float L = fabsf(fire_L[0]);
    if (i < T_SEQ * 32) {
        int t = i >> 5, j = i & 31;
        float inv = powf(10000.0f, -(float)j / 32.0f);
        float f = (float)t * inv;
        cosT[i] = cosf(f);
        sinT[i] = sinf(f);
    }
    if (i < T_SEQ) {
        rdT[i] = logf(fabsf(c * (float)i) + 1.0f);
        pnT[i] = logf(fabsf(c * fmaxf((float)i, L)) + 1.0f) + 1e-6f;
    }
    if (i < 16) mm[i] = (i & 1) ? -__builtin_inff() : __builtin_inff();
}

// ---------------- FIRE bias(nd) piecewise-linear table, per head ----------------
__global__ __launch_bounds__(256) void fire_table_kernel(float* __restrict__ fireT,
    const float* __restrict__ w1, const float* __restrict__ b1,
    const float* __restrict__ w2, const float* __restrict__ b2,
    const float* __restrict__ fc, const float* __restrict__ fL) {
    int h = blockIdx.x;
    float cc = fabsf(fc[0]), LL = fabsf(fL[0]);
    float pn_min = logf(cc * LL + 1.0f) + 1e-6f;
    float ndmax = logf(cc * 2047.0f + 1.0f) / pn_min;
    float step = (ndmax > 1e-30f) ? (ndmax / (float)FIRE_N) : 0.0f;
    float b2h = b2[h];
    for (int i = threadIdx.x; i < FIRE_N + 1; i += 256) {
        float nd = step * (float)i;
        float acc = b2h;
        #pragma unroll
        for (int j = 0; j < 32; ++j)
            acc += fmaxf(fmaf(nd, w1[j], b1[j]), 0.0f) * w2[j * NH + h];
        fireT[h * (FIRE_N + 1) + i] = acc;
    }
}

// ---------------- fp32 -> bf16 elementwise convert ----------------
__global__ __launch_bounds__(256) void cvt_bf16_kernel(const float* __restrict__ in,
                                                       unsigned short* __restrict__ out, int n4) {
    for (int i = blockIdx.x * 256 + threadIdx.x; i < n4; i += gridDim.x * 256) {
        float4 v = ((const float4*)in)[i];
        ushort4v o;
        o[0] = f2bf(v.x); o[1] = f2bf(v.y); o[2] = f2bf(v.z); o[3] = f2bf(v.w);
        ((ushort4v*)out)[i] = o;
    }
}

// ---------------- transpose + convert: in (R x C fp32) -> out (C x R bf16) ----------------
__global__ __launch_bounds__(256) void transpose_bf16_kernel(const float* __restrict__ in,
                                                             unsigned short* __restrict__ out,
                                                             int R, int C) {
    __shared__ float t[64][65];
    int c0 = blockIdx.x * 64, r0 = blockIdx.y * 64;
    int tid = threadIdx.x;
    int lr = tid >> 6, lc = tid & 63;
    #pragma unroll 4
    for (int i = 0; i < 16; ++i)
        t[lr + 4 * i][lc] = in[(size_t)(r0 + lr + 4 * i) * C + c0 + lc];
    __syncthreads();
    #pragma unroll 4
    for (int i = 0; i < 16; ++i)
        out[(size_t)(c0 + lr + 4 * i) * R + r0 + lc] = f2bf(t[lc][lr + 4 * i]);
}

// ---------------- bf16 MFMA GEMM: C(MxN fp32) = A(MxK bf16) @ Bt(NxK bf16)^T ----------------
__global__ __launch_bounds__(256) void gemm_bf16(const unsigned short* __restrict__ A,
                                                 const unsigned short* __restrict__ Bt,
                                                 float* __restrict__ C,
                                                 int M, int N, int K) {
    __shared__ unsigned short As[128 * 40];
    __shared__ unsigned short Bs[128 * 40];
    const int tid = threadIdx.x;
    const int row0 = blockIdx.y * 128, col0 = blockIdx.x * 128;
    const int wv = tid >> 6, lane = tid & 63;
    const int l15 = lane & 15, l4 = lane >> 4;
    const int wr = (wv >> 1) * 64, wc = (wv & 1) * 64;
    f32x4 acc[4][4];
    #pragma unroll
    for (int n = 0; n < 4; ++n)
        #pragma unroll
        for (int m = 0; m < 4; ++m) acc[n][m] = (f32x4){0.f, 0.f, 0.f, 0.f};

    for (int k0 = 0; k0 < K; k0 += 32) {
        #pragma unroll
        for (int t2 = 0; t2 < 2; ++t2) {
            int c = tid + t2 * 256;
            int r = c >> 2, qq = c & 3;
            uint4 av = *(const uint4*)(A + (size_t)(row0 + r) * K + k0 + qq * 8);
            *(uint4*)(As + r * 40 + qq * 8) = av;
            uint4 bv = *(const uint4*)(Bt + (size_t)(col0 + r) * K + k0 + qq * 8);
            *(uint4*)(Bs + r * 40 + qq * 8) = bv;
        }
        __syncthreads();
        bf16x8 af[4], bfr[4];
        #pragma unroll
        for (int n = 0; n < 4; ++n) af[n] = *(const bf16x8*)(As + (wr + n * 16 + l15) * 40 + l4 * 8);
        #pragma unroll
        for (int m = 0; m < 4; ++m) bfr[m] = *(const bf16x8*)(Bs + (wc + m * 16 + l15) * 40 + l4 * 8);
        #pragma unroll
        for (int n = 0; n < 4; ++n)
            #pragma unroll
            for (int m = 0; m < 4; ++m)
                acc[n][m] = __builtin_amdgcn_mfma_f32_16x16x32_bf16(af[n], bfr[m], acc[n][m], 0, 0, 0);
        __syncthreads();
    }
    #pragma unroll
    for (int n = 0; n < 4; ++n) {
        #pragma unroll
        for (int m = 0; m < 4; ++m) {
            #pragma unroll
            for (int j = 0; j < 4; ++j) {
                C[(size_t)(row0 + wr + n * 16 + l4 * 4 + j) * N + col0 + wc + m * 16 + l15] = acc[n][m][j];
            }
        }
    }
}

// ---------------- RoPE in place + global min/max ----------------
__global__ __launch_bounds__(256) void rope_minmax_kernel(float* __restrict__ x,
                                                          const float* __restrict__ cosT,
                                                          const float* __restrict__ sinT,
                                                          int nh, float* mm) {
    int n = T_SEQ * nh * 32;
    float lmn = __builtin_inff(), lmx = -__builtin_inff();
    for (int i = blockIdx.x * 256 + threadIdx.x; i < n; i += gridDim.x * 256) {
        int d = i & 31;
        int th = i >> 5;
        int h = th % nh;
        int t = th / nh;
        float c = cosT[(t << 5) + d], s = sinT[(t << 5) + d];
        float* p = x + ((size_t)t * nh + h) * 64;
        float x1 = p[d], x2 = p[d + 32];
        float o1 = fmaf(x1, c, -x2 * s);
        float o2 = fmaf(x2, c, x1 * s);
        p[d] = o1;
        p[d + 32] = o2;
        lmn = fminf(lmn, fminf(o1, o2));
        lmx = fmaxf(lmx, fmaxf(o1, o2));
    }
    __shared__ float smn[256], smx[256];
    int tid = threadIdx.x;
    smn[tid] = lmn; smx[tid] = lmx;
    __syncthreads();
    for (int s2 = 128; s2; s2 >>= 1) {
        if (tid < s2) {
            smn[tid] = fminf(smn[tid], smn[tid + s2]);
            smx[tid] = fmaxf(smx[tid], smx[tid + s2]);
        }
        __syncthreads();
    }
    if (tid == 0) { atomicMinF(mm, smn[0]); atomicMaxF(mm + 1, smx[0]); }
}

// ---------------- plain global min/max ----------------
__global__ __launch_bounds__(256) void minmax_kernel(const float* __restrict__ x, int n, float* mm) {
    float lmn = __builtin_inff(), lmx = -__builtin_inff();
    for (int i = blockIdx.x * 256 + threadIdx.x; i < n; i += gridDim.x * 256) {
        float v = x[i];
        lmn = fminf(lmn, v);
        lmx = fmaxf(lmx, v);
    }
    __shared__ float smn[256], smx[256];
    int tid = threadIdx.x;
    smn[tid] = lmn; smx[tid] = lmx;
    __syncthreads();
    for (int s2 = 128; s2; s2 >>= 1) {
        if (tid < s2) {
            smn[tid] = fminf(smn[tid], smn[tid + s2]);
            smx[tid] = fmaxf(smx[tid], smx[tid + s2]);
        }
        __syncthreads();
    }
    if (tid == 0) { atomicMinF(mm, smn[0]); atomicMaxF(mm + 1, smx[0]); }
}

// ---------------- fake-quant fp32 -> bf16 out (for q,k,v,y) ----------------
__global__ __launch_bounds__(256) void quant_bf16_kernel(const float* __restrict__ x, int n,
                                                         const float* __restrict__ mm,
                                                         unsigned short* __restrict__ out) {
    float mn = mm[0], mx = mm[1];
    float scale = (mx - mn) / 255.0f + 1e-12f;
    float zp = rintf(-mn / scale);
    for (int i = blockIdx.x * 256 + threadIdx.x; i < n; i += gridDim.x * 256) {
        float v = x[i];
        float qv = rintf(v / scale) + zp;
        qv = fminf(fmaxf(qv, 0.0f), 255.0f);
        out[i] = f2bf((qv - zp) * scale);
    }
}

// ======================= split-K MFMA flash attention =======================
// Chunking: qt<16 -> 1 chunk (tiles 0..qt); qt>=16 -> 2 chunks (tiles 0..15 | 16..qt).
// 48 chunk-blocks per head. Flat id f: f<16 -> (qt=f,c=0); else g=f-16, qt=16+g/2, c=g&1.
// LPT: f = 47 - blockIdx.x (heavy chunks dispatch first).
__device__ __forceinline__ void chunk_map(int f, int& qt, int& cch, int& t0, int& t1) {
    if (f < 16) { qt = f; cch = 0; } else { int g = f - 16; qt = 16 + (g >> 1); cch = g & 1; }
    t0 = cch << 4;
    int nt = qt + 1;
    t1 = min(nt, t0 + 16);
}

// ---- pass A: per-chunk online (m,l) stats. LDS ~21KB -> high residency. ----
__global__ __launch_bounds__(256) void attn_stats(
    const unsigned short* __restrict__ qb, const unsigned short* __restrict__ kb,
    const float* __restrict__ rdT, const float* __restrict__ pnT,
    const float* __restrict__ fireT,
    const float* __restrict__ fc, const float* __restrict__ fL,
    float* __restrict__ sm, float* __restrict__ sl) {
    __shared__ __align__(16) char Ks[8192];
    __shared__ float biasT[FIRE_N + 1];
    __shared__ float rdS[T_SEQ];

    const int h = blockIdx.y, g = h >> 2;
    int qt, cch, t0, t1;
    chunk_map(47 - (int)blockIdx.x, qt, cch, t0, t1);
    const int q0 = qt << 6;
    const int tid = threadIdx.x;
    const int w = tid >> 6, lane = tid & 63;
    const int l15 = lane & 15, l4 = lane >> 4;

    for (int i = tid; i < FIRE_N + 1; i += 256) biasT[i] = fireT[h * (FIRE_N + 1) + i];
    for (int i = tid; i < T_SEQ; i += 256) rdS[i] = rdT[i];

    float cc = fabsf(fc[0]), LL = fabsf(fL[0]);
    float pn_min = logf(cc * LL + 1.0f) + 1e-6f;
    float ndmax = logf(cc * 2047.0f + 1.0f) / pn_min;
    float inv_step = (ndmax > 1e-30f) ? ((float)FIRE_N / ndmax) : 0.0f;

    int qrow[4]; float invpn[4], mreg[4], lreg[4];
    #pragma unroll
    for (int r = 0; r < 4; ++r) {
        qrow[r] = q0 + (w << 4) + (l4 << 2) + r;
        invpn[r] = 1.0f / pnT[qrow[r]];
        mreg[r] = -3.0e38f; lreg[r] = 0.0f;
    }

    bf16x8 qa[2];
    {
        int qr = q0 + (w << 4) + l15;
        const unsigned short* qp = qb + ((size_t)qr * NH + h) * HS + (l4 << 3);
        qa[0] = *(const bf16x8*)(qp);
        qa[1] = *(const bf16x8*)(qp + 32);
    }

    const int krow = tid >> 2, kqtr = tid & 3;
    const int ksw = (krow & 7) << 4;
    uint4 kRa, kRb;
    auto loadK = [&](int tt) {
        const unsigned short* kp = kb + (((size_t)((tt << 6) + krow) * NKV + g) << 6) + (kqtr << 4);
        kRa = *(const uint4*)(kp);
        kRb = *(const uint4*)(kp + 8);
    };
    auto storeK = [&]() {
        *(uint4*)(Ks + krow * 128 + ((kqtr << 5) ^ ksw)) = kRa;
        *(uint4*)(Ks + krow * 128 + (((kqtr << 5) + 16) ^ ksw)) = kRb;
    };

    loadK(t0); storeK();
    __syncthreads();
    for (int tt = t0; tt < t1; ++tt) {
        if (tt + 1 < t1) loadK(tt + 1);
        f32x4 s[4];
        #pragma unroll
        for (int n = 0; n < 4; ++n) s[n] = (f32x4){0.f, 0.f, 0.f, 0.f};
        #pragma unroll
        for (int ks = 0; ks < 2; ++ks) {
            int cb = (l4 << 4) + (ks << 6);
            #pragma unroll
            for (int n = 0; n < 4; ++n) {
                int rowk = (n << 4) + l15;
                bf16x8 kf = *(const bf16x8*)(Ks + rowk * 128 + (cb ^ ((rowk & 7) << 4)));
                s[n] = __builtin_amdgcn_mfma_f32_16x16x32_bf16(qa[ks], kf, s[n], 0, 0, 0);
            }
        }
        #pragma unroll
        for (int n = 0; n < 4; ++n) {
            int kidx = (tt << 6) + (n << 4) + l15;
            #pragma unroll
            for (int r = 0; r < 4; ++r) {
                float v;
                if (kidx <= qrow[r]) {
                    float nd = rdS[qrow[r] - kidx] * invpn[r];
                    float u = nd * inv_step;
                    int iu = (int)u; iu = min(iu, FIRE_N - 1);
                    float fr = u - (float)iu;
                    float b0 = biasT[iu];
                    v = fmaf(s[n][r], 0.125f, fmaf(fr, biasT[iu + 1] - b0, b0));
                } else v = -3.0e38f;
                s[n][r] = v;
            }
        }
        #pragma unroll
        for (int r = 0; r < 4; ++r) {
            float tmax = fmaxf(fmaxf(s[0][r], s[1][r]), fmaxf(s[2][r], s[3][r]));
            tmax = fmaxf(tmax, __shfl_xor(tmax, 1));
            tmax = fmaxf(tmax, __shfl_xor(tmax, 2));
            tmax = fmaxf(tmax, __shfl_xor(tmax, 4));
            tmax = fmaxf(tmax, __shfl_xor(tmax, 8));
            float mnew = fmaxf(mreg[r], tmax);
            float es = __expf(s[0][r] - mnew) + __expf(s[1][r] - mnew)
                     + __expf(s[2][r] - mnew) + __expf(s[3][r] - mnew);
            es += __shfl_xor(es, 1); es += __shfl_xor(es, 2);
            es += __shfl_xor(es, 4); es += __shfl_xor(es, 8);
            lreg[r] = lreg[r] * __expf(mreg[r] - mnew) + es;
            mreg[r] = mnew;
        }
        __syncthreads();
        if (tt + 1 < t1) { storeK(); __syncthreads(); }
    }

    if (l15 == 0) {
        int base = (((h * 32 + qt) * 2) + cch) * 64 + (w << 4) + (l4 << 2);
        #pragma unroll
        for (int r = 0; r < 4; ++r) { sm[base + r] = mreg[r]; sl[base + r] = lreg[r]; }
    }
}

// ---- combine: final (m, l) per row ----
__global__ __launch_bounds__(64) void attn_combine(const float* __restrict__ sm,
                                                   const float* __restrict__ sl,
                                                   float* __restrict__ mf, float* __restrict__ lf) {
    int qt = blockIdx.x, h = blockIdx.y, local = threadIdx.x;
    int i0 = ((h * 32 + qt) * 2) * 64 + local;
    float m0 = sm[i0], l0 = sl[i0];
    float m, l;
    if (qt >= 16) {
        float m1 = sm[i0 + 64], l1 = sl[i0 + 64];
        m = fmaxf(m0, m1);
        l = l0 * __expf(m0 - m) + l1 * __expf(m1 - m);
    } else { m = m0; l = l0; }
    mf[(h * 32 + qt) * 64 + local] = m;
    lf[(h * 32 + qt) * 64 + local] = l;
}

// ---- pass B: quantized PV per chunk. c==1 writes partials (summed by attn_reduce). ----
__global__ __launch_bounds__(256) void attn_pv(
    const unsigned short* __restrict__ qb, const unsigned short* __restrict__ kb,
    const unsigned short* __restrict__ vb, float* __restrict__ y,
    const float* __restrict__ rdT, const float* __restrict__ pnT,
    const float* __restrict__ fireT,
    const float* __restrict__ fc, const float* __restrict__ fL,
    const float* __restrict__ mf, const float* __restrict__ lf,
    float* __restrict__ pb) {
    __shared__ __align__(16) char Ks[8192];
    __shared__ __align__(16) char Vt[8192];
    __shared__ __align__(16) char Ps[8192];
    __shared__ float biasT[FIRE_N + 1];
    __shared__ float rdS[T_SEQ];

    const int h = blockIdx.y, g = h >> 2;
    int qt, cch, t0, t1;
    chunk_map(47 - (int)blockIdx.x, qt, cch, t0, t1);
    const int q0 = qt << 6;
    const int tid = threadIdx.x;
    const int w = tid >> 6, lane = tid & 63;
    const int l15 = lane & 15, l4 = lane >> 4;

    for (int i = tid; i < FIRE_N + 1; i += 256) biasT[i] = fireT[h * (FIRE_N + 1) + i];
    for (int i = tid; i < T_SEQ; i += 256) rdS[i] = rdT[i];

    float cc = fabsf(fc[0]), LL = fabsf(fL[0]);
    float pn_min = logf(cc * LL + 1.0f) + 1e-6f;
    float ndmax = logf(cc * 2047.0f + 1.0f) / pn_min;
    float inv_step = (ndmax > 1e-30f) ? ((float)FIRE_N / ndmax) : 0.0f;

    int qrow[4]; float invpn[4], mreg[4], invl[4];
    #pragma unroll
    for (int r = 0; r < 4; ++r) {
        qrow[r] = q0 + (w << 4) + (l4 << 2) + r;
        invpn[r] = 1.0f / pnT[qrow[r]];
        int fi = (h * 32 + qt) * 64 + (w << 4) + (l4 << 2) + r;
        mreg[r] = mf[fi];
        invl[r] = 1.0f / lf[fi];
    }

    bf16x8 qa[2];
    {
        int qr = q0 + (w << 4) + l15;
        const unsigned short* qp = qb + ((size_t)qr * NH + h) * HS + (l4 << 3);
        qa[0] = *(const bf16x8*)(qp);
        qa[1] = *(const bf16x8*)(qp + 32);
    }

    const int krow = tid >> 2, kqtr = tid & 3;
    const int ksw = (krow & 7) << 4;
    const int vk = tid & 63, vd0 = (tid >> 6) << 4;
    uint4 kRa, kRb, vRa, vRb;
    auto loadK = [&](int tt) {
        const unsigned short* kp = kb + (((size_t)((tt << 6) + krow) * NKV + g) << 6) + (kqtr << 4);
        kRa = *(const uint4*)(kp);
        kRb = *(const uint4*)(kp + 8);
    };
    auto storeK = [&]() {
        *(uint4*)(Ks + krow * 128 + ((kqtr << 5) ^ ksw)) = kRa;
        *(uint4*)(Ks + krow * 128 + (((kqtr << 5) + 16) ^ ksw)) = kRb;
    };
    auto loadV = [&](int tt) {
        const unsigned short* vp = vb + (((size_t)((tt << 6) + vk) * NKV + g) << 6) + vd0;
        vRa = *(const uint4*)(vp);
        vRb = *(const uint4*)(vp + 8);
    };
    auto storeV = [&]() {
        unsigned int wv2[8] = {vRa.x, vRa.y, vRa.z, vRa.w, vRb.x, vRb.y, vRb.z, vRb.w};
        int k2 = vk << 1;
        #pragma unroll
        for (int i = 0; i < 8; ++i) {
            int d = vd0 + (i << 1);
            *(unsigned short*)(Vt + d * 128 + (k2 ^ ((d & 7) << 4))) = (unsigned short)(wv2[i] & 0xffff);
            int d1 = d + 1;
            *(unsigned short*)(Vt + d1 * 128 + (k2 ^ ((d1 & 7) << 4))) = (unsigned short)(wv2[i] >> 16);
        }
    };

    f32x4 yacc[4];
    #pragma unroll
    for (int n = 0; n < 4; ++n) yacc[n] = (f32x4){0.f, 0.f, 0.f, 0.f};

    loadK(t0); loadV(t0); storeK(); storeV();
    __syncthreads();
    for (int tt = t0; tt < t1; ++tt) {
        if (tt + 1 < t1) { loadK(tt + 1); loadV(tt + 1); }
        f32x4 s[4];
        #pragma unroll
        for (int n = 0; n < 4; ++n) s[n] = (f32x4){0.f, 0.f, 0.f, 0.f};
        #pragma unroll
        for (int ks = 0; ks < 2; ++ks) {
            int cb = (l4 << 4) + (ks << 6);
            #pragma unroll
            for (int n = 0; n < 4; ++n) {
                int rowk = (n << 4) + l15;
                bf16x8 kf = *(const bf16x8*)(Ks + rowk * 128 + (cb ^ ((rowk & 7) << 4)));
                s[n] = __builtin_amdgcn_mfma_f32_16x16x32_bf16(qa[ks], kf, s[n], 0, 0, 0);
            }
        }
        #pragma unroll
        for (int n = 0; n < 4; ++n) {
            int kidx = (tt << 6) + (n << 4) + l15;
            #pragma unroll
            for (int r = 0; r < 4; ++r) {
                float v;
                if (kidx <= qrow[r]) {
                    float nd = rdS[qrow[r] - kidx] * invpn[r];
                    float u = nd * inv_step;
                    int iu = (int)u; iu = min(iu, FIRE_N - 1);
                    float fr = u - (float)iu;
                    float b0 = biasT[iu];
                    v = fmaf(s[n][r], 0.125f, fmaf(fr, biasT[iu + 1] - b0, b0));
                } else v = -3.0e38f;
                s[n][r] = v;
            }
        }
        // p = exp(s-m)/l, quantize to 1/255 grid (exact: post-softmax min=0,max=1)
        #pragma unroll
        for (int n = 0; n < 4; ++n) {
            #pragma unroll
            for (int r = 0; r < 4; ++r) {
                float p = __expf(s[n][r] - mreg[r]) * invl[r];
                float ph = fminf(rintf(p * 255.0f), 255.0f) * (1.0f / 255.0f);
                int rowp = (w << 4) + (l4 << 2) + r;
                *(unsigned short*)(Ps + rowp * 128 + ((((n << 4) + l15) << 1) ^ ((rowp & 7) << 4))) = f2bf(ph);
            }
        }
        #pragma unroll
        for (int ks = 0; ks < 2; ++ks) {
            int rowp = (w << 4) + l15;
            int cb = (l4 << 4) + (ks << 6);
            bf16x8 pa = *(const bf16x8*)(Ps + rowp * 128 + (cb ^ ((rowp & 7) << 4)));
            #pragma unroll
            for (int n2 = 0; n2 < 4; ++n2) {
                int d = (n2 << 4) + l15;
                bf16x8 vf = *(const bf16x8*)(Vt + d * 128 + (cb ^ ((d & 7) << 4)));
                yacc[n2] = __builtin_amdgcn_mfma_f32_16x16x32_bf16(pa, vf, yacc[n2], 0, 0, 0);
            }
        }
        __syncthreads();
        if (tt + 1 < t1) { storeK(); storeV(); __syncthreads(); }
    }

    if (cch == 0) {
        #pragma unroll
        for (int n2 = 0; n2 < 4; ++n2)
            #pragma unroll
            for (int r = 0; r < 4; ++r)
                y[((size_t)qrow[r] * NH + h) * HS + (n2 << 4) + l15] = yacc[n2][r];
    } else {
        int pbase = (h * 16 + (qt - 16)) * 4096;
        #pragma unroll
        for (int n2 = 0; n2 < 4; ++n2)
            #pragma unroll
            for (int r = 0; r < 4; ++r)
                pb[pbase + ((w << 4) + (l4 << 2) + r) * 64 + (n2 << 4) + l15] = yacc[n2][r];
    }
}

// ---- reduce: add c=1 partials into y (qt>=16 only) ----
__global__ __launch_bounds__(256) void attn_reduce(float* __restrict__ y,
                                                   const float* __restrict__ pb) {
    const int n = 16 * 16 * 4096;   // heads x qts(16..31) x 64rows x 64d
    for (int idx = blockIdx.x * 256 + threadIdx.x; idx < n; idx += gridDim.x * 256) {
        int h = idx >> 16;
        int rem = idx & 65535;
        int qtl = rem >> 12;
        int e = rem & 4095;
        int lr = e >> 6, d = e & 63;
        size_t yi = ((size_t)((16 + qtl) * 64 + lr) * NH + h) * HS + d;
        y[yi] += pb[idx];
    }
}

extern "C" void kernel_launch(void* const* d_in, const int* in_sizes, int n_in,
                              void* d_out, int out_size, void* d_ws, size_t ws_size,
                              hipStream_t stream) {
    const float* x     = (const float*)d_in[0];
    const float* Wq    = (const float*)d_in[1];
    const float* Wk    = (const float*)d_in[2];
    const float* Wv    = (const float*)d_in[3];
    const float* Wproj = (const float*)d_in[4];
    const float* fw1   = (const float*)d_in[5];
    const float* fb1   = (const float*)d_in[6];
    const float* fw2   = (const float*)d_in[7];
    const float* fb2   = (const float*)d_in[8];
    const float* fc    = (const float*)d_in[9];
    const float* fL    = (const float*)d_in[10];
    float* out = (float*)d_out;

    float* ws   = (float*)d_ws;
    float* qf   = ws;                  // (T,16,64) fp32 q; REUSED as y after quant
    float* kkf  = qf + 2097152;        // (T,4,64) fp32
    float* vvf  = kkf + 524288;
    float* cosT = vvf + 524288;
    float* sinT = cosT + 65536;
    float* rdT  = sinT + 65536;
    float* pnT  = rdT + 2048;
    float* mm   = pnT + 2048;          // [qmn,qmx,kmn,kmx,vmn,vmx,ymn,ymx]
    float* fireT = mm + 16;            // 16*(FIRE_N+1)
    unsigned short* qb  = (unsigned short*)(fireT + 16 * (FIRE_N + 1));
    unsigned short* kb  = qb + 2097152;
    unsigned short* vb  = kb + 524288;
    unsigned short* xb  = vb + 524288;       // (T,1024) bf16; REUSED as yb
    unsigned short* Wqt = xb + 2097152;      // (1024,1024) bf16 transposed
    unsigned short* Wkt = Wqt + 1048576;     // (256,1024)
    unsigned short* Wvt = Wkt + 262144;      // (256,1024)
    unsigned short* Wpt = Wvt + 262144;      // (1024,1024)
    float* sm   = (float*)(Wpt + 1048576);   // 65536 (h,qt,c,row) partial m
    float* sl   = sm + 65536;                // 65536 partial l
    float* mfin = sl + 65536;                // 32768 final m
    float* lfin = mfin + 32768;              // 32768 final l
    float* pb   = lfin + 32768;              // 1048576 c=1 partial yacc (16h x 16qt x 64 x 64)
    float* y  = qf;                    // alias: q fp32 dead after quant_bf16
    unsigned short* yb = xb;           // alias: xb dead after projections

    init_kernel<<<256, 256, 0, stream>>>(cosT, sinT, rdT, pnT, mm, fc, fL);
    fire_table_kernel<<<16, 256, 0, stream>>>(fireT, fw1, fb1, fw2, fb2, fc, fL);

    // convert x and transpose+convert weights to bf16
    cvt_bf16_kernel<<<1024, 256, 0, stream>>>(x, xb, 524288);
    transpose_bf16_kernel<<<dim3(16, 16), 256, 0, stream>>>(Wq, Wqt, 1024, 1024);
    transpose_bf16_kernel<<<dim3(4, 16), 256, 0, stream>>>(Wk, Wkt, 1024, 256);
    transpose_bf16_kernel<<<dim3(4, 16), 256, 0, stream>>>(Wv, Wvt, 1024, 256);
    transpose_bf16_kernel<<<dim3(16, 16), 256, 0, stream>>>(Wproj, Wpt, 1024, 1024);

    // projections (MFMA)
    gemm_bf16<<<dim3(8, 16), 256, 0, stream>>>(xb, Wqt, qf, T_SEQ, CDIM, CDIM);
    gemm_bf16<<<dim3(2, 16), 256, 0, stream>>>(xb, Wkt, kkf, T_SEQ, 256, CDIM);
    gemm_bf16<<<dim3(2, 16), 256, 0, stream>>>(xb, Wvt, vvf, T_SEQ, 256, CDIM);

    rope_minmax_kernel<<<1024, 256, 0, stream>>>(qf, cosT, sinT, NH, mm + 0);
    rope_minmax_kernel<<<512, 256, 0, stream>>>(kkf, cosT, sinT, NKV, mm + 2);
    minmax_kernel<<<512, 256, 0, stream>>>(vvf, 524288, mm + 4);

    quant_bf16_kernel<<<1024, 256, 0, stream>>>(qf, 2097152, mm + 0, qb);
    quant_bf16_kernel<<<512, 256, 0, stream>>>(kkf, 524288, mm + 2, kb);
    quant_bf16_kernel<<<512, 256, 0, stream>>>(vvf, 524288, mm + 4, vb);

    // split-K attention
    attn_stats<<<dim3(48, 16), 256, 0, stream>>>(qb, kb, rdT, pnT, fireT, fc, fL, sm, sl);
    attn_combine<<<dim3(32, 16), 64, 0, stream>>>(sm, sl, mfin, lfin);
    attn_pv<<<dim3(48, 16), 256, 0, stream>>>(qb, kb, vb, y, rdT, pnT, fireT, fc, fL, mfin, lfin, pb);
    attn_reduce<<<1024, 256, 0, stream>>>(y, pb);

    minmax_kernel<<<1024, 256, 0, stream>>>(y, 2097152, mm + 6);
    quant_bf16_kernel<<<1024, 256, 0, stream>>>(y, 2097152, mm + 6, yb);

    // output projection (MFMA)
    gemm_bf16<<<dim3(8, 16), 256, 0, stream>>>(yb, Wpt, out, T_SEQ, CDIM, CDIM);
}

// Round 12
// 356.377 us; speedup vs baseline: 1.4642x; 1.2989x over previous
//
#include <hip/hip_runtime.h>
#include <math.h>

#define T_SEQ 2048
#define CDIM 1024
#define NH 16
#define NKV 4
#define HS 64
#define FIRE_N 1024   // interpolation intervals; table has FIRE_N+1 entries

typedef __attribute__((ext_vector_type(8))) short bf16x8;
typedef __attribute__((ext_vector_type(4))) float f32x4;
typedef __attribute__((ext_vector_type(4))) unsigned short ushort4v;

__device__ __forceinline__ unsigned short f2bf(float f) {
    unsigned int u = __float_as_uint(f);
    u += 0x7fff + ((u >> 16) & 1);   // RNE
    return (unsigned short)(u >> 16);
}

// ---------------- init: rope tables, FIRE 1-D tables, minmax slots ----------------
__global__ __launch_bounds__(256) void init_kernel(float* cosT, float* sinT, float* rdT,
                                                   float* pnT, float* mm,
                                                   const float* fire_c, const float* fire_L) {
    int i = blockIdx.x * 256 + threadIdx.x;
    float c = fire_c[0];
    float L = fabsf(fire_L[0]);
    if (i < T_SEQ * 32) {
        int t = i >> 5, j = i & 31;
        float inv = powf(10000.0f, -(float)j / 32.0f);
        float f = (float)t * inv;
        cosT[i] = cosf(f);
        sinT[i] = sinf(f);
    }
    if (i < T_SEQ) {
        rdT[i] = logf(fabsf(c * (float)i) + 1.0f);
        pnT[i] = logf(fabsf(c * fmaxf((float)i, L)) + 1.0f) + 1e-6f;
    }
    if (i < 16) mm[i] = (i & 1) ? -__builtin_inff() : __builtin_inff();
}

// ---------------- FIRE bias(nd) piecewise-linear table, per head ----------------
__global__ __launch_bounds__(256) void fire_table_kernel(float* __restrict__ fireT,
    const float* __restrict__ w1, const float* __restrict__ b1,
    const float* __restrict__ w2, const float* __restrict__ b2,
    const float* __restrict__ fc, const float* __restrict__ fL) {
    int h = blockIdx.x;
    float cc = fabsf(fc[0]), LL = fabsf(fL[0]);
    float pn_min = logf(cc * LL + 1.0f) + 1e-6f;
    float ndmax = logf(cc * 2047.0f + 1.0f) / pn_min;
    float step = (ndmax > 1e-30f) ? (ndmax / (float)FIRE_N) : 0.0f;
    float b2h = b2[h];
    for (int i = threadIdx.x; i < FIRE_N + 1; i += 256) {
        float nd = step * (float)i;
        float acc = b2h;
        #pragma unroll
        for (int j = 0; j < 32; ++j)
            acc += fmaxf(fmaf(nd, w1[j], b1[j]), 0.0f) * w2[j * NH + h];
        fireT[h * (FIRE_N + 1) + i] = acc;
    }
}

// ---------------- fp32 -> bf16 elementwise convert ----------------
__global__ __launch_bounds__(256) void cvt_bf16_kernel(const float* __restrict__ in,
                                                       unsigned short* __restrict__ out, int n4) {
    for (int i = blockIdx.x * 256 + threadIdx.x; i < n4; i += gridDim.x * 256) {
        float4 v = ((const float4*)in)[i];
        ushort4v o;
        o[0] = f2bf(v.x); o[1] = f2bf(v.y); o[2] = f2bf(v.z); o[3] = f2bf(v.w);
        ((ushort4v*)out)[i] = o;
    }
}

// ---------------- transpose + convert: in (R x C fp32) -> out (C x R bf16) ----------------
__global__ __launch_bounds__(256) void transpose_bf16_kernel(const float* __restrict__ in,
                                                             unsigned short* __restrict__ out,
                                                             int R, int C) {
    __shared__ float t[64][65];
    int c0 = blockIdx.x * 64, r0 = blockIdx.y * 64;
    int tid = threadIdx.x;
    int lr = tid >> 6, lc = tid & 63;
    #pragma unroll 4
    for (int i = 0; i < 16; ++i)
        t[lr + 4 * i][lc] = in[(size_t)(r0 + lr + 4 * i) * C + c0 + lc];
    __syncthreads();
    #pragma unroll 4
    for (int i = 0; i < 16; ++i)
        out[(size_t)(c0 + lr + 4 * i) * R + r0 + lc] = f2bf(t[lc][lr + 4 * i]);
}

// ---------------- bf16 MFMA GEMM: C(MxN fp32) = A(MxK bf16) @ Bt(NxK bf16)^T ----------------
__global__ __launch_bounds__(256) void gemm_bf16(const unsigned short* __restrict__ A,
                                                 const unsigned short* __restrict__ Bt,
                                                 float* __restrict__ C,
                                                 int M, int N, int K) {
    __shared__ unsigned short As[128 * 40];
    __shared__ unsigned short Bs[128 * 40];
    const int tid = threadIdx.x;
    const int row0 = blockIdx.y * 128, col0 = blockIdx.x * 128;
    const int wv = tid >> 6, lane = tid & 63;
    const int l15 = lane & 15, l4 = lane >> 4;
    const int wr = (wv >> 1) * 64, wc = (wv & 1) * 64;
    f32x4 acc[4][4];
    #pragma unroll
    for (int n = 0; n < 4; ++n)
        #pragma unroll
        for (int m = 0; m < 4; ++m) acc[n][m] = (f32x4){0.f, 0.f, 0.f, 0.f};

    for (int k0 = 0; k0 < K; k0 += 32) {
        #pragma unroll
        for (int t2 = 0; t2 < 2; ++t2) {
            int c = tid + t2 * 256;
            int r = c >> 2, qq = c & 3;
            uint4 av = *(const uint4*)(A + (size_t)(row0 + r) * K + k0 + qq * 8);
            *(uint4*)(As + r * 40 + qq * 8) = av;
            uint4 bv = *(const uint4*)(Bt + (size_t)(col0 + r) * K + k0 + qq * 8);
            *(uint4*)(Bs + r * 40 + qq * 8) = bv;
        }
        __syncthreads();
        bf16x8 af[4], bfr[4];
        #pragma unroll
        for (int n = 0; n < 4; ++n) af[n] = *(const bf16x8*)(As + (wr + n * 16 + l15) * 40 + l4 * 8);
        #pragma unroll
        for (int m = 0; m < 4; ++m) bfr[m] = *(const bf16x8*)(Bs + (wc + m * 16 + l15) * 40 + l4 * 8);
        #pragma unroll
        for (int n = 0; n < 4; ++n)
            #pragma unroll
            for (int m = 0; m < 4; ++m)
                acc[n][m] = __builtin_amdgcn_mfma_f32_16x16x32_bf16(af[n], bfr[m], acc[n][m], 0, 0, 0);
        __syncthreads();
    }
    #pragma unroll
    for (int n = 0; n < 4; ++n) {
        #pragma unroll
        for (int m = 0; m < 4; ++m) {
            #pragma unroll
            for (int j = 0; j < 4; ++j) {
                C[(size_t)(row0 + wr + n * 16 + l4 * 4 + j) * N + col0 + wc + m * 16 + l15] = acc[n][m][j];
            }
        }
    }
}

// ---------------- RoPE in place (float4) + per-block min/max partials ----------------
// Work item = 4 rotation pairs. x: (T, nh, 64). No global atomics.
__global__ __launch_bounds__(256) void rope_minmax_part(float* __restrict__ x,
                                                        const float* __restrict__ cosT,
                                                        const float* __restrict__ sinT,
                                                        int nh,
                                                        float* __restrict__ pmn, float* __restrict__ pmx) {
    int nitems = T_SEQ * nh * 8;
    float lmn = __builtin_inff(), lmx = -__builtin_inff();
    for (int i = blockIdx.x * 256 + threadIdx.x; i < nitems; i += gridDim.x * 256) {
        int d0 = (i & 7) << 2;
        int th = i >> 3;
        int h = th % nh;
        int t = th / nh;
        float4 c4 = *(const float4*)(cosT + (t << 5) + d0);
        float4 s4 = *(const float4*)(sinT + (t << 5) + d0);
        float* p = x + ((size_t)t * nh + h) * 64;
        float4 a = *(const float4*)(p + d0);
        float4 b = *(const float4*)(p + d0 + 32);
        float4 o1, o2;
        o1.x = fmaf(a.x, c4.x, -b.x * s4.x);  o2.x = fmaf(b.x, c4.x, a.x * s4.x);
        o1.y = fmaf(a.y, c4.y, -b.y * s4.y);  o2.y = fmaf(b.y, c4.y, a.y * s4.y);
        o1.z = fmaf(a.z, c4.z, -b.z * s4.z);  o2.z = fmaf(b.z, c4.z, a.z * s4.z);
        o1.w = fmaf(a.w, c4.w, -b.w * s4.w);  o2.w = fmaf(b.w, c4.w, a.w * s4.w);
        *(float4*)(p + d0) = o1;
        *(float4*)(p + d0 + 32) = o2;
        lmn = fminf(lmn, fminf(fminf(o1.x, o1.y), fminf(o1.z, o1.w)));
        lmn = fminf(lmn, fminf(fminf(o2.x, o2.y), fminf(o2.z, o2.w)));
        lmx = fmaxf(lmx, fmaxf(fmaxf(o1.x, o1.y), fmaxf(o1.z, o1.w)));
        lmx = fmaxf(lmx, fmaxf(fmaxf(o2.x, o2.y), fmaxf(o2.z, o2.w)));
    }
    __shared__ float smn[256], smx[256];
    int tid = threadIdx.x;
    smn[tid] = lmn; smx[tid] = lmx;
    __syncthreads();
    for (int s2 = 128; s2; s2 >>= 1) {
        if (tid < s2) {
            smn[tid] = fminf(smn[tid], smn[tid + s2]);
            smx[tid] = fmaxf(smx[tid], smx[tid + s2]);
        }
        __syncthreads();
    }
    if (tid == 0) { pmn[blockIdx.x] = smn[0]; pmx[blockIdx.x] = smx[0]; }
}

// ---------------- float4 min/max with per-block partials ----------------
__global__ __launch_bounds__(256) void minmax_part(const float* __restrict__ x, int n4,
                                                   float* __restrict__ pmn, float* __restrict__ pmx) {
    float lmn = __builtin_inff(), lmx = -__builtin_inff();
    for (int i = blockIdx.x * 256 + threadIdx.x; i < n4; i += gridDim.x * 256) {
        float4 v = ((const float4*)x)[i];
        lmn = fminf(lmn, fminf(fminf(v.x, v.y), fminf(v.z, v.w)));
        lmx = fmaxf(lmx, fmaxf(fmaxf(v.x, v.y), fmaxf(v.z, v.w)));
    }
    __shared__ float smn[256], smx[256];
    int tid = threadIdx.x;
    smn[tid] = lmn; smx[tid] = lmx;
    __syncthreads();
    for (int s2 = 128; s2; s2 >>= 1) {
        if (tid < s2) {
            smn[tid] = fminf(smn[tid], smn[tid + s2]);
            smx[tid] = fmaxf(smx[tid], smx[tid + s2]);
        }
        __syncthreads();
    }
    if (tid == 0) { pmn[blockIdx.x] = smn[0]; pmx[blockIdx.x] = smx[0]; }
}

// ---------------- combine partials -> mm slots (1 block; jobs j cover [offs[j],offs[j+1])) ----------------
__global__ __launch_bounds__(256) void combine_mm(const float* __restrict__ pmn,
                                                  const float* __restrict__ pmx,
                                                  int o0, int o1, int o2, int o3,
                                                  int njobs, float* __restrict__ mmb) {
    __shared__ float smn[256], smx[256];
    int offs[4] = {o0, o1, o2, o3};
    int tid = threadIdx.x;
    for (int j = 0; j < njobs; ++j) {
        float mn = __builtin_inff(), mx = -__builtin_inff();
        for (int i = offs[j] + tid; i < offs[j + 1]; i += 256) {
            mn = fminf(mn, pmn[i]); mx = fmaxf(mx, pmx[i]);
        }
        smn[tid] = mn; smx[tid] = mx;
        __syncthreads();
        for (int s2 = 128; s2; s2 >>= 1) {
            if (tid < s2) {
                smn[tid] = fminf(smn[tid], smn[tid + s2]);
                smx[tid] = fmaxf(smx[tid], smx[tid + s2]);
            }
            __syncthreads();
        }
        if (tid == 0) { mmb[2 * j] = smn[0]; mmb[2 * j + 1] = smx[0]; }
        __syncthreads();
    }
}

// ---------------- fake-quant fp32 -> bf16, float4/ushort4 ----------------
__global__ __launch_bounds__(256) void quant_bf16_v4(const float* __restrict__ x, int n4,
                                                     const float* __restrict__ mm2,
                                                     unsigned short* __restrict__ out) {
    float mn = mm2[0], mx = mm2[1];
    float scale = (mx - mn) / 255.0f + 1e-12f;
    float zp = rintf(-mn / scale);
    for (int i = blockIdx.x * 256 + threadIdx.x; i < n4; i += gridDim.x * 256) {
        float4 v = ((const float4*)x)[i];
        ushort4v o;
        float q0 = fminf(fmaxf(rintf(v.x / scale) + zp, 0.0f), 255.0f);
        float q1 = fminf(fmaxf(rintf(v.y / scale) + zp, 0.0f), 255.0f);
        float q2 = fminf(fmaxf(rintf(v.z / scale) + zp, 0.0f), 255.0f);
        float q3 = fminf(fmaxf(rintf(v.w / scale) + zp, 0.0f), 255.0f);
        o[0] = f2bf((q0 - zp) * scale);
        o[1] = f2bf((q1 - zp) * scale);
        o[2] = f2bf((q2 - zp) * scale);
        o[3] = f2bf((q3 - zp) * scale);
        ((ushort4v*)out)[i] = o;
    }
}

// ======================= split-K MFMA flash attention =======================
__device__ __forceinline__ void chunk_map(int f, int& qt, int& cch, int& t0, int& t1) {
    if (f < 16) { qt = f; cch = 0; } else { int g = f - 16; qt = 16 + (g >> 1); cch = g & 1; }
    t0 = cch << 4;
    int nt = qt + 1;
    t1 = min(nt, t0 + 16);
}

// ---- pass A: per-chunk online (m,l) stats ----
__global__ __launch_bounds__(256) void attn_stats(
    const unsigned short* __restrict__ qb, const unsigned short* __restrict__ kb,
    const float* __restrict__ rdT, const float* __restrict__ pnT,
    const float* __restrict__ fireT,
    const float* __restrict__ fc, const float* __restrict__ fL,
    float* __restrict__ sm, float* __restrict__ sl) {
    __shared__ __align__(16) char Ks[8192];
    __shared__ float biasT[FIRE_N + 1];
    __shared__ float rdS[T_SEQ];

    const int h = blockIdx.y, g = h >> 2;
    int qt, cch, t0, t1;
    chunk_map(47 - (int)blockIdx.x, qt, cch, t0, t1);
    const int q0 = qt << 6;
    const int tid = threadIdx.x;
    const int w = tid >> 6, lane = tid & 63;
    const int l15 = lane & 15, l4 = lane >> 4;

    for (int i = tid; i < FIRE_N + 1; i += 256) biasT[i] = fireT[h * (FIRE_N + 1) + i];
    for (int i = tid; i < T_SEQ; i += 256) rdS[i] = rdT[i];

    float cc = fabsf(fc[0]), LL = fabsf(fL[0]);
    float pn_min = logf(cc * LL + 1.0f) + 1e-6f;
    float ndmax = logf(cc * 2047.0f + 1.0f) / pn_min;
    float inv_step = (ndmax > 1e-30f) ? ((float)FIRE_N / ndmax) : 0.0f;

    int qrow[4]; float invpn[4], mreg[4], lreg[4];
    #pragma unroll
    for (int r = 0; r < 4; ++r) {
        qrow[r] = q0 + (w << 4) + (l4 << 2) + r;
        invpn[r] = 1.0f / pnT[qrow[r]];
        mreg[r] = -3.0e38f; lreg[r] = 0.0f;
    }

    bf16x8 qa[2];
    {
        int qr = q0 + (w << 4) + l15;
        const unsigned short* qp = qb + ((size_t)qr * NH + h) * HS + (l4 << 3);
        qa[0] = *(const bf16x8*)(qp);
        qa[1] = *(const bf16x8*)(qp + 32);
    }

    const int krow = tid >> 2, kqtr = tid & 3;
    const int ksw = (krow & 7) << 4;
    uint4 kRa, kRb;
    auto loadK = [&](int tt) {
        const unsigned short* kp = kb + (((size_t)((tt << 6) + krow) * NKV + g) << 6) + (kqtr << 4);
        kRa = *(const uint4*)(kp);
        kRb = *(const uint4*)(kp + 8);
    };
    auto storeK = [&]() {
        *(uint4*)(Ks + krow * 128 + ((kqtr << 5) ^ ksw)) = kRa;
        *(uint4*)(Ks + krow * 128 + (((kqtr << 5) + 16) ^ ksw)) = kRb;
    };

    loadK(t0); storeK();
    __syncthreads();
    for (int tt = t0; tt < t1; ++tt) {
        if (tt + 1 < t1) loadK(tt + 1);
        f32x4 s[4];
        #pragma unroll
        for (int n = 0; n < 4; ++n) s[n] = (f32x4){0.f, 0.f, 0.f, 0.f};
        #pragma unroll
        for (int ks = 0; ks < 2; ++ks) {
            int cb = (l4 << 4) + (ks << 6);
            #pragma unroll
            for (int n = 0; n < 4; ++n) {
                int rowk = (n << 4) + l15;
                bf16x8 kf = *(const bf16x8*)(Ks + rowk * 128 + (cb ^ ((rowk & 7) << 4)));
                s[n] = __builtin_amdgcn_mfma_f32_16x16x32_bf16(qa[ks], kf, s[n], 0, 0, 0);
            }
        }
        #pragma unroll
        for (int n = 0; n < 4; ++n) {
            int kidx = (tt << 6) + (n << 4) + l15;
            #pragma unroll
            for (int r = 0; r < 4; ++r) {
                float v;
                if (kidx <= qrow[r]) {
                    float nd = rdS[qrow[r] - kidx] * invpn[r];
                    float u = nd * inv_step;
                    int iu = (int)u; iu = min(iu, FIRE_N - 1);
                    float fr = u - (float)iu;
                    float b0 = biasT[iu];
                    v = fmaf(s[n][r], 0.125f, fmaf(fr, biasT[iu + 1] - b0, b0));
                } else v = -3.0e38f;
                s[n][r] = v;
            }
        }
        #pragma unroll
        for (int r = 0; r < 4; ++r) {
            float tmax = fmaxf(fmaxf(s[0][r], s[1][r]), fmaxf(s[2][r], s[3][r]));
            tmax = fmaxf(tmax, __shfl_xor(tmax, 1));
            tmax = fmaxf(tmax, __shfl_xor(tmax, 2));
            tmax = fmaxf(tmax, __shfl_xor(tmax, 4));
            tmax = fmaxf(tmax, __shfl_xor(tmax, 8));
            float mnew = fmaxf(mreg[r], tmax);
            float es = __expf(s[0][r] - mnew) + __expf(s[1][r] - mnew)
                     + __expf(s[2][r] - mnew) + __expf(s[3][r] - mnew);
            es += __shfl_xor(es, 1); es += __shfl_xor(es, 2);
            es += __shfl_xor(es, 4); es += __shfl_xor(es, 8);
            lreg[r] = lreg[r] * __expf(mreg[r] - mnew) + es;
            mreg[r] = mnew;
        }
        __syncthreads();
        if (tt + 1 < t1) { storeK(); __syncthreads(); }
    }

    if (l15 == 0) {
        int base = (((h * 32 + qt) * 2) + cch) * 64 + (w << 4) + (l4 << 2);
        #pragma unroll
        for (int r = 0; r < 4; ++r) { sm[base + r] = mreg[r]; sl[base + r] = lreg[r]; }
    }
}

// ---- combine: final (m, l) per row ----
__global__ __launch_bounds__(64) void attn_combine(const float* __restrict__ sm,
                                                   const float* __restrict__ sl,
                                                   float* __restrict__ mf, float* __restrict__ lf) {
    int qt = blockIdx.x, h = blockIdx.y, local = threadIdx.x;
    int i0 = ((h * 32 + qt) * 2) * 64 + local;
    float m0 = sm[i0], l0 = sl[i0];
    float m, l;
    if (qt >= 16) {
        float m1 = sm[i0 + 64], l1 = sl[i0 + 64];
        m = fmaxf(m0, m1);
        l = l0 * __expf(m0 - m) + l1 * __expf(m1 - m);
    } else { m = m0; l = l0; }
    mf[(h * 32 + qt) * 64 + local] = m;
    lf[(h * 32 + qt) * 64 + local] = l;
}

// ---- pass B: quantized PV per chunk. c==1 writes partials ----
__global__ __launch_bounds__(256) void attn_pv(
    const unsigned short* __restrict__ qb, const unsigned short* __restrict__ kb,
    const unsigned short* __restrict__ vb, float* __restrict__ y,
    const float* __restrict__ rdT, const float* __restrict__ pnT,
    const float* __restrict__ fireT,
    const float* __restrict__ fc, const float* __restrict__ fL,
    const float* __restrict__ mf, const float* __restrict__ lf,
    float* __restrict__ pb) {
    __shared__ __align__(16) char Ks[8192];
    __shared__ __align__(16) char Vt[8192];
    __shared__ __align__(16) char Ps[8192];
    __shared__ float biasT[FIRE_N + 1];
    __shared__ float rdS[T_SEQ];

    const int h = blockIdx.y, g = h >> 2;
    int qt, cch, t0, t1;
    chunk_map(47 - (int)blockIdx.x, qt, cch, t0, t1);
    const int q0 = qt << 6;
    const int tid = threadIdx.x;
    const int w = tid >> 6, lane = tid & 63;
    const int l15 = lane & 15, l4 = lane >> 4;

    for (int i = tid; i < FIRE_N + 1; i += 256) biasT[i] = fireT[h * (FIRE_N + 1) + i];
    for (int i = tid; i < T_SEQ; i += 256) rdS[i] = rdT[i];

    float cc = fabsf(fc[0]), LL = fabsf(fL[0]);
    float pn_min = logf(cc * LL + 1.0f) + 1e-6f;
    float ndmax = logf(cc * 2047.0f + 1.0f) / pn_min;
    float inv_step = (ndmax > 1e-30f) ? ((float)FIRE_N / ndmax) : 0.0f;

    int qrow[4]; float invpn[4], mreg[4], invl[4];
    #pragma unroll
    for (int r = 0; r < 4; ++r) {
        qrow[r] = q0 + (w << 4) + (l4 << 2) + r;
        invpn[r] = 1.0f / pnT[qrow[r]];
        int fi = (h * 32 + qt) * 64 + (w << 4) + (l4 << 2) + r;
        mreg[r] = mf[fi];
        invl[r] = 1.0f / lf[fi];
    }

    bf16x8 qa[2];
    {
        int qr = q0 + (w << 4) + l15;
        const unsigned short* qp = qb + ((size_t)qr * NH + h) * HS + (l4 << 3);
        qa[0] = *(const bf16x8*)(qp);
        qa[1] = *(const bf16x8*)(qp + 32);
    }

    const int krow = tid >> 2, kqtr = tid & 3;
    const int ksw = (krow & 7) << 4;
    const int vk = tid & 63, vd0 = (tid >> 6) << 4;
    uint4 kRa, kRb, vRa, vRb;
    auto loadK = [&](int tt) {
        const unsigned short* kp = kb + (((size_t)((tt << 6) + krow) * NKV + g) << 6) + (kqtr << 4);
        kRa = *(const uint4*)(kp);
        kRb = *(const uint4*)(kp + 8);
    };
    auto storeK = [&]() {
        *(uint4*)(Ks + krow * 128 + ((kqtr << 5) ^ ksw)) = kRa;
        *(uint4*)(Ks + krow * 128 + (((kqtr << 5) + 16) ^ ksw)) = kRb;
    };
    auto loadV = [&](int tt) {
        const unsigned short* vp = vb + (((size_t)((tt << 6) + vk) * NKV + g) << 6) + vd0;
        vRa = *(const uint4*)(vp);
        vRb = *(const uint4*)(vp + 8);
    };
    auto storeV = [&]() {
        unsigned int wv2[8] = {vRa.x, vRa.y, vRa.z, vRa.w, vRb.x, vRb.y, vRb.z, vRb.w};
        int k2 = vk << 1;
        #pragma unroll
        for (int i = 0; i < 8; ++i) {
            int d = vd0 + (i << 1);
            *(unsigned short*)(Vt + d * 128 + (k2 ^ ((d & 7) << 4))) = (unsigned short)(wv2[i] & 0xffff);
            int d1 = d + 1;
            *(unsigned short*)(Vt + d1 * 128 + (k2 ^ ((d1 & 7) << 4))) = (unsigned short)(wv2[i] >> 16);
        }
    };

    f32x4 yacc[4];
    #pragma unroll
    for (int n = 0; n < 4; ++n) yacc[n] = (f32x4){0.f, 0.f, 0.f, 0.f};

    loadK(t0); loadV(t0); storeK(); storeV();
    __syncthreads();
    for (int tt = t0; tt < t1; ++tt) {
        if (tt + 1 < t1) { loadK(tt + 1); loadV(tt + 1); }
        f32x4 s[4];
        #pragma unroll
        for (int n = 0; n < 4; ++n) s[n] = (f32x4){0.f, 0.f, 0.f, 0.f};
        #pragma unroll
        for (int ks = 0; ks < 2; ++ks) {
            int cb = (l4 << 4) + (ks << 6);
            #pragma unroll
            for (int n = 0; n < 4; ++n) {
                int rowk = (n << 4) + l15;
                bf16x8 kf = *(const bf16x8*)(Ks + rowk * 128 + (cb ^ ((rowk & 7) << 4)));
                s[n] = __builtin_amdgcn_mfma_f32_16x16x32_bf16(qa[ks], kf, s[n], 0, 0, 0);
            }
        }
        #pragma unroll
        for (int n = 0; n < 4; ++n) {
            int kidx = (tt << 6) + (n << 4) + l15;
            #pragma unroll
            for (int r = 0; r < 4; ++r) {
                float v;
                if (kidx <= qrow[r]) {
                    float nd = rdS[qrow[r] - kidx] * invpn[r];
                    float u = nd * inv_step;
                    int iu = (int)u; iu = min(iu, FIRE_N - 1);
                    float fr = u - (float)iu;
                    float b0 = biasT[iu];
                    v = fmaf(s[n][r], 0.125f, fmaf(fr, biasT[iu + 1] - b0, b0));
                } else v = -3.0e38f;
                s[n][r] = v;
            }
        }
        #pragma unroll
        for (int n = 0; n < 4; ++n) {
            #pragma unroll
            for (int r = 0; r < 4; ++r) {
                float p = __expf(s[n][r] - mreg[r]) * invl[r];
                float ph = fminf(rintf(p * 255.0f), 255.0f) * (1.0f / 255.0f);
                int rowp = (w << 4) + (l4 << 2) + r;
                *(unsigned short*)(Ps + rowp * 128 + ((((n << 4) + l15) << 1) ^ ((rowp & 7) << 4))) = f2bf(ph);
            }
        }
        #pragma unroll
        for (int ks = 0; ks < 2; ++ks) {
            int rowp = (w << 4) + l15;
            int cb = (l4 << 4) + (ks << 6);
            bf16x8 pa = *(const bf16x8*)(Ps + rowp * 128 + (cb ^ ((rowp & 7) << 4)));
            #pragma unroll
            for (int n2 = 0; n2 < 4; ++n2) {
                int d = (n2 << 4) + l15;
                bf16x8 vf = *(const bf16x8*)(Vt + d * 128 + (cb ^ ((d & 7) << 4)));
                yacc[n2] = __builtin_amdgcn_mfma_f32_16x16x32_bf16(pa, vf, yacc[n2], 0, 0, 0);
            }
        }
        __syncthreads();
        if (tt + 1 < t1) { storeK(); storeV(); __syncthreads(); }
    }

    if (cch == 0) {
        #pragma unroll
        for (int n2 = 0; n2 < 4; ++n2)
            #pragma unroll
            for (int r = 0; r < 4; ++r)
                y[((size_t)qrow[r] * NH + h) * HS + (n2 << 4) + l15] = yacc[n2][r];
    } else {
        int pbase = (h * 16 + (qt - 16)) * 4096;
        #pragma unroll
        for (int n2 = 0; n2 < 4; ++n2)
            #pragma unroll
            for (int r = 0; r < 4; ++r)
                pb[pbase + ((w << 4) + (l4 << 2) + r) * 64 + (n2 << 4) + l15] = yacc[n2][r];
    }
}

// ---- reduce c=1 partials into y + fused y min/max partials (float4) ----
// y flat index f = t_row*1024 + h*64 + d.
__global__ __launch_bounds__(256) void attn_reduce_mm(float* __restrict__ y,
                                                      const float* __restrict__ pb,
                                                      float* __restrict__ pmn, float* __restrict__ pmx) {
    const int n4 = 524288;   // 2M / 4
    float lmn = __builtin_inff(), lmx = -__builtin_inff();
    for (int i = blockIdx.x * 256 + threadIdx.x; i < n4; i += gridDim.x * 256) {
        int f = i << 2;
        int t = f >> 10;
        int rem = f & 1023;
        int h = rem >> 6, d0 = rem & 63;
        float4 v = *(const float4*)(y + f);
        if (t >= 1024) {
            int qtl = (t >> 6) - 16, rrow = t & 63;
            const float4 p4 = *(const float4*)(pb + ((size_t)(h * 16 + qtl) * 64 + rrow) * 64 + d0);
            v.x += p4.x; v.y += p4.y; v.z += p4.z; v.w += p4.w;
            *(float4*)(y + f) = v;
        }
        lmn = fminf(lmn, fminf(fminf(v.x, v.y), fminf(v.z, v.w)));
        lmx = fmaxf(lmx, fmaxf(fmaxf(v.x, v.y), fmaxf(v.z, v.w)));
    }
    __shared__ float smn[256], smx[256];
    int tid = threadIdx.x;
    smn[tid] = lmn; smx[tid] = lmx;
    __syncthreads();
    for (int s2 = 128; s2; s2 >>= 1) {
        if (tid < s2) {
            smn[tid] = fminf(smn[tid], smn[tid + s2]);
            smx[tid] = fmaxf(smx[tid], smx[tid + s2]);
        }
        __syncthreads();
    }
    if (tid == 0) { pmn[blockIdx.x] = smn[0]; pmx[blockIdx.x] = smx[0]; }
}

extern "C" void kernel_launch(void* const* d_in, const int* in_sizes, int n_in,
                              void* d_out, int out_size, void* d_ws, size_t ws_size,
                              hipStream_t stream) {
    const float* x     = (const float*)d_in[0];
    const float* Wq    = (const float*)d_in[1];
    const float* Wk    = (const float*)d_in[2];
    const float* Wv    = (const float*)d_in[3];
    const float* Wproj = (const float*)d_in[4];
    const float* fw1   = (const float*)d_in[5];
    const float* fb1   = (const float*)d_in[6];
    const float* fw2   = (const float*)d_in[7];
    const float* fb2   = (const float*)d_in[8];
    const float* fc    = (const float*)d_in[9];
    const float* fL    = (const float*)d_in[10];
    float* out = (float*)d_out;

    float* ws   = (float*)d_ws;
    float* qf   = ws;                  // (T,16,64) fp32 q; REUSED as y after quant
    float* kkf  = qf + 2097152;        // (T,4,64) fp32
    float* vvf  = kkf + 524288;
    float* cosT = vvf + 524288;
    float* sinT = cosT + 65536;
    float* rdT  = sinT + 65536;
    float* pnT  = rdT + 2048;
    float* mm   = pnT + 2048;          // [qmn,qmx,kmn,kmx,vmn,vmx,ymn,ymx]
    float* fireT = mm + 16;            // 16*(FIRE_N+1)
    unsigned short* qb  = (unsigned short*)(fireT + 16 * (FIRE_N + 1));
    unsigned short* kb  = qb + 2097152;
    unsigned short* vb  = kb + 524288;
    unsigned short* xb  = vb + 524288;       // (T,1024) bf16; REUSED as yb
    unsigned short* Wqt = xb + 2097152;      // (1024,1024) bf16 transposed
    unsigned short* Wkt = Wqt + 1048576;     // (256,1024)
    unsigned short* Wvt = Wkt + 262144;      // (256,1024)
    unsigned short* Wpt = Wvt + 262144;      // (1024,1024)
    float* sm   = (float*)(Wpt + 1048576);   // 65536 partial m
    float* sl   = sm + 65536;                // 65536 partial l
    float* mfin = sl + 65536;                // 32768 final m
    float* lfin = mfin + 32768;              // 32768 final l
    float* pb   = lfin + 32768;              // 1048576 c=1 partial yacc
    float* pmn  = pb + 1048576;              // 896 partial mins: q[0,512) k[512,640) v[640,896)
    float* pmx  = pmn + 896;                 // 896 partial maxs
    float* pyn  = pmx + 896;                 // 512 y partial mins
    float* pyx  = pyn + 512;                 // 512 y partial maxs
    float* y  = qf;                    // alias: q fp32 dead after quant
    unsigned short* yb = xb;           // alias: xb dead after projections

    init_kernel<<<256, 256, 0, stream>>>(cosT, sinT, rdT, pnT, mm, fc, fL);
    fire_table_kernel<<<16, 256, 0, stream>>>(fireT, fw1, fb1, fw2, fb2, fc, fL);

    // convert x and transpose+convert weights to bf16
    cvt_bf16_kernel<<<1024, 256, 0, stream>>>(x, xb, 524288);
    transpose_bf16_kernel<<<dim3(16, 16), 256, 0, stream>>>(Wq, Wqt, 1024, 1024);
    transpose_bf16_kernel<<<dim3(4, 16), 256, 0, stream>>>(Wk, Wkt, 1024, 256);
    transpose_bf16_kernel<<<dim3(4, 16), 256, 0, stream>>>(Wv, Wvt, 1024, 256);
    transpose_bf16_kernel<<<dim3(16, 16), 256, 0, stream>>>(Wproj, Wpt, 1024, 1024);

    // projections (MFMA)
    gemm_bf16<<<dim3(8, 16), 256, 0, stream>>>(xb, Wqt, qf, T_SEQ, CDIM, CDIM);
    gemm_bf16<<<dim3(2, 16), 256, 0, stream>>>(xb, Wkt, kkf, T_SEQ, 256, CDIM);
    gemm_bf16<<<dim3(2, 16), 256, 0, stream>>>(xb, Wvt, vvf, T_SEQ, 256, CDIM);

    // rope + min/max partials (no atomics), then single combine
    rope_minmax_part<<<512, 256, 0, stream>>>(qf, cosT, sinT, NH, pmn, pmx);
    rope_minmax_part<<<128, 256, 0, stream>>>(kkf, cosT, sinT, NKV, pmn + 512, pmx + 512);
    minmax_part<<<256, 256, 0, stream>>>(vvf, 131072, pmn + 640, pmx + 640);
    combine_mm<<<1, 256, 0, stream>>>(pmn, pmx, 0, 512, 640, 896, 3, mm);

    quant_bf16_v4<<<512, 256, 0, stream>>>(qf, 524288, mm + 0, qb);
    quant_bf16_v4<<<128, 256, 0, stream>>>(kkf, 131072, mm + 2, kb);
    quant_bf16_v4<<<128, 256, 0, stream>>>(vvf, 131072, mm + 4, vb);

    // split-K attention
    attn_stats<<<dim3(48, 16), 256, 0, stream>>>(qb, kb, rdT, pnT, fireT, fc, fL, sm, sl);
    attn_combine<<<dim3(32, 16), 64, 0, stream>>>(sm, sl, mfin, lfin);
    attn_pv<<<dim3(48, 16), 256, 0, stream>>>(qb, kb, vb, y, rdT, pnT, fireT, fc, fL, mfin, lfin, pb);

    // reduce partials into y + fused y min/max, then combine + quant
    attn_reduce_mm<<<512, 256, 0, stream>>>(y, pb, pyn, pyx);
    combine_mm<<<1, 256, 0, stream>>>(pyn, pyx, 0, 512, 0, 0, 1, mm + 6);
    quant_bf16_v4<<<512, 256, 0, stream>>>(y, 524288, mm + 6, yb);

    // output projection (MFMA)
    gemm_bf16<<<dim3(8, 16), 256, 0, stream>>>(yb, Wpt, out, T_SEQ, CDIM, CDIM);
}